// Round 10
// baseline (387.383 us; speedup 1.0000x reference)
//
#include <hip/hip_runtime.h>

#define D 128
#define LDA 136   // LDS agg row stride in ushorts: 272B, 16B-aligned
#define ECAP 3072 // staged edge-index capacity per block (mean 2048, sd~45)

typedef __attribute__((ext_vector_type(8))) short bf16x8;
typedef __attribute__((ext_vector_type(4))) float f32x4;

__device__ __forceinline__ ushort f2b(float f) {
  union { float f; unsigned u; } a; a.f = f;
  unsigned u = a.u;
  return (ushort)((u + 0x7fffu + ((u >> 16) & 1u)) >> 16);  // RNE
}
__device__ __forceinline__ float b2f_lo(unsigned v) {
  union { unsigned u; float f; } a; a.u = v << 16; return a.f;
}
__device__ __forceinline__ float b2f_hi(unsigned v) {
  union { unsigned u; float f; } a; a.u = v & 0xffff0000u; return a.f;
}

// ---------- merged prep: x->bf16 padded, weights->bf16, zero cnt+sums ----------
__global__ void k_prep(const float* __restrict__ x, const float* __restrict__ wl,
                       const float* __restrict__ wr, const float* __restrict__ w1,
                       const float* __restrict__ w2, ushort* __restrict__ hb,
                       ushort* __restrict__ wall, uint4* __restrict__ zr,
                       int nX4, int npX4, int LDD, int nZero4) {
  int i = blockIdx.x * blockDim.x + threadIdx.x;
  if (i < npX4) {
    uint2 pk;
    if (i < nX4) {
      float4 v = *(const float4*)&x[i * 4];
      pk.x = (unsigned)f2b(v.x) | ((unsigned)f2b(v.y) << 16);
      pk.y = (unsigned)f2b(v.z) | ((unsigned)f2b(v.w) << 16);
    } else {
      pk = make_uint2(0u, 0u);
    }
    *(uint2*)&hb[i * 4] = pk;
    return;
  }
  int j = i - npX4;
  int W = 2 * LDD + 2 * D * D;
  if (j < W) {
    float v;
    if (j < LDD) v = wl[j];
    else if (j < 2 * LDD) v = wr[j - LDD];
    else if (j < 2 * LDD + D * D) v = w1[j - 2 * LDD];
    else v = w2[j - 2 * LDD - D * D];
    wall[j] = f2b(v);
    return;
  }
  int z = j - W;
  if (z < nZero4) zr[z] = make_uint4(0u, 0u, 0u, 0u);
}

// ---------- CSR build ----------
__global__ void k_histrank(const int* __restrict__ dstI, int* __restrict__ cnt,
                           int* __restrict__ rankdst, int E) {
  int e = blockIdx.x * blockDim.x + threadIdx.x;
  if (e < E) {
    int d = dstI[e];
    int r = atomicAdd(&cnt[d], 1);
    rankdst[e] = (r << 16) | d;
  }
}
__global__ void k_scan1(const int* __restrict__ cnt, int* __restrict__ off,
                        int* __restrict__ bsum, int n) {
  __shared__ int sd[256];
  int t = threadIdx.x;
  int i = blockIdx.x * 256 + t;
  int x = (i < n) ? cnt[i] : 0;
  sd[t] = x;
  __syncthreads();
  for (int s = 1; s < 256; s <<= 1) {
    int v = (t >= s) ? sd[t - s] : 0;
    __syncthreads();
    sd[t] += v;
    __syncthreads();
  }
  if (i < n) off[i] = sd[t] - x;
  if (t == 255) bsum[blockIdx.x] = sd[255];
}
__global__ void k_scan2(const int* __restrict__ bsum, int* __restrict__ boff, int nb) {
  __shared__ int sd[256];
  int t = threadIdx.x;
  int x = (t < nb) ? bsum[t] : 0;
  sd[t] = x;
  __syncthreads();
  for (int s = 1; s < 256; s <<= 1) {
    int v = (t >= s) ? sd[t - s] : 0;
    __syncthreads();
    sd[t] += v;
    __syncthreads();
  }
  if (t < nb) boff[t] = sd[t] - x;
}
__global__ void k_scan3(int* __restrict__ off, const int* __restrict__ boff, int n) {
  int i = blockIdx.x * blockDim.x + threadIdx.x;
  if (i < n) off[i] += boff[i >> 8];
}
// non-atomic scatter fill, ushort payload
__global__ void k_fill(const int* __restrict__ srcI, const int* __restrict__ rankdst,
                       const int* __restrict__ off, ushort* __restrict__ eidx, int E) {
  int e = blockIdx.x * blockDim.x + threadIdx.x;
  if (e < E) {
    int rd = rankdst[e];
    int d = rd & 0xFFFF;
    eidx[off[d] + (rd >> 16)] = (ushort)srcI[e];
  }
}

#define ACC8(A, V, B)                                             \
  A[B + 0] += b2f_lo(V.x); A[B + 1] += b2f_hi(V.x);               \
  A[B + 2] += b2f_lo(V.y); A[B + 3] += b2f_hi(V.y);               \
  A[B + 4] += b2f_lo(V.z); A[B + 5] += b2f_hi(V.z);               \
  A[B + 6] += b2f_lo(V.w); A[B + 7] += b2f_hi(V.w);

// ---------- fused: [stage eidx->LDS] + [gather-mean -> LDS] + dual GEMM + bias + col-stats
// 1024 threads (16 waves), 128x128 tile. Gather: 8 threads/row, 16 feats (32B) each.
// Block's edge range [off[r0], off[r0+128)) is contiguous (CSR row-sorted) -> staged
// coalesced into LDS; gather loop reads indices via ds_read (removes the global
// eidx load from the dependent chain; only the random h-load stays global).
// GEMM: 4x4 wave grid, 32x32 per wave, acc[2][2], mfma_f32_16x16x32_bf16.
template <bool AGG>
__global__ __launch_bounds__(1024, 8) void k_fused(
    const ushort* __restrict__ hin, const ushort* __restrict__ Wl,
    const ushort* __restrict__ Wr, const float* __restrict__ bias,
    const int* __restrict__ off, const ushort* __restrict__ eidx,
    ushort* __restrict__ pre, float* __restrict__ sums, int N, int E) {
  __shared__ ushort aggS[128 * LDA];
  __shared__ ushort eidxS[ECAP];
  __shared__ float ls[2 * D];
  int t = threadIdx.x;
  int r0 = blockIdx.x * 128;

  if (t < 2 * D) ls[t] = 0.f;

  if (AGG) {
    // stage this block's contiguous edge-index range into LDS
    int eBase = off[r0];
    int eEnd = (r0 + 128 < N) ? off[r0 + 128] : E;
    int cnt = eEnd - eBase;
    for (int i = t; i < cnt && i < ECAP; i += 1024) eidxS[i] = eidx[eBase + i];
    __syncthreads();

    // gather-mean into LDS: 8 threads per row, 16 features (32B) each
    int lrow = t >> 3;
    int row = r0 + lrow;
    int part = (t & 7) << 4;
    float a[16];
#pragma unroll
    for (int i = 0; i < 16; ++i) a[i] = 0.f;
    int start = 0, end = 0;
    if (row < N) { start = off[row]; end = (row == N - 1) ? E : off[row + 1]; }
    const ushort* hbase = hin + part;
    if (cnt <= ECAP) {
#pragma unroll 4
      for (int e = start; e < end; ++e) {
        int sn = eidxS[e - eBase];
        const uint4* p = (const uint4*)(hbase + (size_t)sn * D);
        uint4 v0 = p[0], v1 = p[1];
        ACC8(a, v0, 0) ACC8(a, v1, 8)
      }
    } else {  // statistically unreachable fallback
#pragma unroll 2
      for (int e = start; e < end; ++e) {
        int sn = eidx[e];
        const uint4* p = (const uint4*)(hbase + (size_t)sn * D);
        uint4 v0 = p[0], v1 = p[1];
        ACC8(a, v0, 0) ACC8(a, v1, 8)
      }
    }
    int deg = end - start;
    float inv = (deg > 0) ? 1.0f / (float)deg : 0.f;
    unsigned o[8];
#pragma unroll
    for (int i = 0; i < 8; ++i)
      o[i] = (unsigned)f2b(a[2 * i] * inv) | ((unsigned)f2b(a[2 * i + 1] * inv) << 16);
    uint4* dst = (uint4*)&aggS[lrow * LDA + part];
    dst[0] = make_uint4(o[0], o[1], o[2], o[3]);
    dst[1] = make_uint4(o[4], o[5], o[6], o[7]);
  }
  __syncthreads();

  // MFMA phase: 16 waves, 4 row-groups x 4 col-groups, 32x32 per wave
  int lane = t & 63;
  int wid = t >> 6;
  int wr = wid >> 2, wc = wid & 3;
  int rw = wr * 32, cw = wc * 32;
  int lr = lane & 15, lk = (lane >> 4) * 8;

  f32x4 acc[2][2];
#pragma unroll
  for (int i = 0; i < 2; ++i)
#pragma unroll
    for (int j = 0; j < 2; ++j) acc[i][j] = (f32x4){0.f, 0.f, 0.f, 0.f};

#pragma unroll
  for (int ks = 0; ks < 4; ++ks) {
    int kb = ks * 32 + lk;
    bf16x8 aA[2], aB[2];
#pragma unroll
    for (int rt = 0; rt < 2; ++rt) {
      if (AGG) {
        aA[rt] = *(const bf16x8*)&aggS[(rw + rt * 16 + lr) * LDA + kb];
        aB[rt] = *(const bf16x8*)&hin[(size_t)(r0 + rw + rt * 16 + lr) * D + kb];
      } else {
        aA[rt] = *(const bf16x8*)&hin[(size_t)(r0 + rw + rt * 16 + lr) * D + kb];
      }
    }
#pragma unroll
    for (int jt = 0; jt < 2; ++jt) {
      bf16x8 b1 = *(const bf16x8*)&Wl[(size_t)(cw + jt * 16 + lr) * D + kb];
      acc[0][jt] = __builtin_amdgcn_mfma_f32_16x16x32_bf16(aA[0], b1, acc[0][jt], 0, 0, 0);
      acc[1][jt] = __builtin_amdgcn_mfma_f32_16x16x32_bf16(aA[1], b1, acc[1][jt], 0, 0, 0);
      if (AGG) {
        bf16x8 b2 = *(const bf16x8*)&Wr[(size_t)(cw + jt * 16 + lr) * D + kb];
        acc[0][jt] = __builtin_amdgcn_mfma_f32_16x16x32_bf16(aB[0], b2, acc[0][jt], 0, 0, 0);
        acc[1][jt] = __builtin_amdgcn_mfma_f32_16x16x32_bf16(aB[1], b2, acc[1][jt], 0, 0, 0);
      }
    }
  }

  // bias + write pre (bf16) + column stats
  int crow = (lane >> 4) * 4;
#pragma unroll
  for (int jt = 0; jt < 2; ++jt) {
    int col = cw + jt * 16 + lr;
    float bv = bias[col];
    float s1 = 0.f, s2 = 0.f;
#pragma unroll
    for (int rt = 0; rt < 2; ++rt) {
      int rbase = r0 + rw + rt * 16 + crow;
#pragma unroll
      for (int rg = 0; rg < 4; ++rg) {
        int row = rbase + rg;
        if (row < N) {
          float v = acc[rt][jt][rg] + bv;
          pre[(size_t)row * D + col] = f2b(v);
          s1 += v; s2 += v * v;
        }
      }
    }
    s1 += __shfl_xor(s1, 16, 64); s1 += __shfl_xor(s1, 32, 64);
    s2 += __shfl_xor(s2, 16, 64); s2 += __shfl_xor(s2, 32, 64);
    if (lane < 16) {
      atomicAdd(&ls[cw + jt * 16 + lane], s1);
      atomicAdd(&ls[D + cw + jt * 16 + lane], s2);
    }
  }
  __syncthreads();
  if (t < 2 * D) atomicAdd(&sums[t], ls[t]);
}

// ---------- BN + ReLU from bf16 pre; writes bf16 next-activation, opt fp32 ----------
template <bool F32OUT>
__global__ void k_bnrelu(const ushort* __restrict__ pre, const float* __restrict__ sums,
                         const float* __restrict__ gamma, const float* __restrict__ beta,
                         float* __restrict__ fout, ushort* __restrict__ bout,
                         int N, int Np, float invN) {
  int i4 = blockIdx.x * blockDim.x + threadIdx.x;
  if (i4 >= Np * (D / 4)) return;
  int row = i4 >> 5;
  int c4 = (i4 & 31) * 4;
  uint2 pk;
  if (row < N) {
    uint2 pv = *(const uint2*)&pre[(size_t)row * D + c4];
    float4 v = make_float4(b2f_lo(pv.x), b2f_hi(pv.x), b2f_lo(pv.y), b2f_hi(pv.y));
    float4 s = *(const float4*)&sums[c4];
    float4 q = *(const float4*)&sums[D + c4];
    float4 g = *(const float4*)&gamma[c4];
    float4 b = *(const float4*)&beta[c4];
    float mu, var, sc, sh;
    mu = s.x * invN; var = fmaxf(q.x * invN - mu * mu, 0.f);
    sc = g.x * rsqrtf(var + 1e-5f); sh = b.x - mu * sc;
    v.x = fmaxf(fmaf(v.x, sc, sh), 0.f);
    mu = s.y * invN; var = fmaxf(q.y * invN - mu * mu, 0.f);
    sc = g.y * rsqrtf(var + 1e-5f); sh = b.y - mu * sc;
    v.y = fmaxf(fmaf(v.y, sc, sh), 0.f);
    mu = s.z * invN; var = fmaxf(q.z * invN - mu * mu, 0.f);
    sc = g.z * rsqrtf(var + 1e-5f); sh = b.z - mu * sc;
    v.z = fmaxf(fmaf(v.z, sc, sh), 0.f);
    mu = s.w * invN; var = fmaxf(q.w * invN - mu * mu, 0.f);
    sc = g.w * rsqrtf(var + 1e-5f); sh = b.w - mu * sc;
    v.w = fmaxf(fmaf(v.w, sc, sh), 0.f);
    if (F32OUT) *(float4*)&fout[(size_t)row * D + c4] = v;
    pk.x = (unsigned)f2b(v.x) | ((unsigned)f2b(v.y) << 16);
    pk.y = (unsigned)f2b(v.z) | ((unsigned)f2b(v.w) << 16);
  } else {
    pk = make_uint2(0u, 0u);
  }
  *(uint2*)&bout[(size_t)row * D + c4] = pk;
}

// ---------- final GEMM: atom = (z @ W2.T + b2) * mask, fp32 out ----------
__global__ __launch_bounds__(256) void k_mmfin(
    const ushort* __restrict__ A, const ushort* __restrict__ W,
    const float* __restrict__ bias, const float* __restrict__ mask,
    float* __restrict__ out, int N) {
  int t = threadIdx.x;
  int lane = t & 63;
  int wid = t >> 6;
  int wr = wid >> 1, wc = wid & 1;
  int r0 = blockIdx.x * 128 + wr * 64;
  int c0 = wc * 64;
  int lr = lane & 15, lk = (lane >> 4) * 8;

  f32x4 acc[4][4];
#pragma unroll
  for (int i = 0; i < 4; ++i)
#pragma unroll
    for (int j = 0; j < 4; ++j) acc[i][j] = (f32x4){0.f, 0.f, 0.f, 0.f};

#pragma unroll
  for (int ks = 0; ks < 4; ++ks) {
    int kb = ks * 32 + lk;
    bf16x8 a1[4];
#pragma unroll
    for (int rt = 0; rt < 4; ++rt)
      a1[rt] = *(const bf16x8*)&A[(size_t)(r0 + rt * 16 + lr) * D + kb];
#pragma unroll
    for (int jt = 0; jt < 4; ++jt) {
      bf16x8 b1 = *(const bf16x8*)&W[(size_t)(c0 + jt * 16 + lr) * D + kb];
#pragma unroll
      for (int rt = 0; rt < 4; ++rt)
        acc[rt][jt] = __builtin_amdgcn_mfma_f32_16x16x32_bf16(a1[rt], b1, acc[rt][jt], 0, 0, 0);
    }
  }

  int crow = (lane >> 4) * 4;
#pragma unroll
  for (int rt = 0; rt < 4; ++rt) {
    int rbase = r0 + rt * 16 + crow;
#pragma unroll
    for (int jt = 0; jt < 4; ++jt) {
      int col = c0 + jt * 16 + lr;
      float bv = bias[col];
#pragma unroll
      for (int rg = 0; rg < 4; ++rg) {
        int row = rbase + rg;
        if (row < N) {
          float m = mask[row];
          out[(size_t)row * D + col] = (acc[rt][jt][rg] + bv) * m;
        }
      }
    }
  }
}

// ---------- state gather ----------
__global__ void k_gather(const float* __restrict__ h, const int* __restrict__ uidx,
                         float* __restrict__ outp, int U) {
  int u = blockIdx.x;
  int t = threadIdx.x;  // 32 threads
  int s = uidx[u];
  *(float4*)&outp[(size_t)u * D + t * 4] = *(const float4*)&h[(size_t)s * D + t * 4];
}

extern "C" void kernel_launch(void* const* d_in, const int* in_sizes, int n_in,
                              void* d_out, int out_size, void* d_ws, size_t ws_size,
                              hipStream_t stream) {
  const float* x        = (const float*)d_in[0];
  const int*   edge     = (const int*)d_in[1];
  const float* amask    = (const float*)d_in[2];
  const int*   uindex   = (const int*)d_in[3];
  const float* lin_l_w  = (const float*)d_in[4];
  const float* lin_l_b  = (const float*)d_in[5];
  const float* lin_r_w  = (const float*)d_in[6];
  const float* bn_gamma = (const float*)d_in[7];
  const float* bn_beta  = (const float*)d_in[8];
  const float* ro_w1    = (const float*)d_in[9];
  const float* ro_b1    = (const float*)d_in[10];
  const float* ro_bng   = (const float*)d_in[11];
  const float* ro_bnb   = (const float*)d_in[12];
  const float* ro_w2    = (const float*)d_in[13];
  const float* ro_b2    = (const float*)d_in[14];

  const int N = in_sizes[0] / D;
  const int E = in_sizes[1] / 2;
  const int U = in_sizes[3];
  const int L = in_sizes[4] / (D * D);
  const int Np = ((N + 127) / 128) * 128;
  const int LDD = L * D * D;

  const int* srcI = edge;
  const int* dstI = edge + E;

  float* outH     = (float*)d_out;               // [N][D]
  float* outAtom  = outH + (size_t)N * D;        // [N][D]
  float* outState = outAtom + (size_t)N * D;     // [U][D]

  // workspace carve (cnt and sums contiguous for the fused zeroing; 16B aligned)
  char* w = (char*)d_ws;
  ushort* hb   = (ushort*)w; w += (size_t)Np * D * 2;
  ushort* pre  = (ushort*)w; w += (size_t)Np * D * 2;
  ushort* wall = (ushort*)w; w += (size_t)(2 * LDD + 2 * D * D) * 2;
  int*    cnt  = (int*)w;    w += (size_t)N * 4;
  float*  sums = (float*)w;  w += 4 * 2 * D * 4;   // sums0..sums3
  int* off     = (int*)w;    w += (size_t)N * 4;
  int* rankdst = (int*)w;    w += (size_t)E * 4;
  ushort* eidx = (ushort*)w; w += (size_t)((E + 1) & ~1) * 2;
  int* bsum    = (int*)w;    w += 1024;
  int* boff    = (int*)w;    w += 1024;

  ushort* wlb = wall;
  ushort* wrb = wlb + (size_t)LDD;
  ushort* w1b = wrb + (size_t)LDD;
  ushort* w2b = w1b + (size_t)D * D;

  const float invN = 1.0f / (float)N;

  // 1) merged prep: x cast, weight casts, zero cnt+sums
  {
    int nX4 = N * D / 4, npX4 = Np * D / 4;
    int W = 2 * LDD + 2 * D * D;
    int nZero4 = (N + 4 * 2 * D) / 4;           // cnt (N ints) + sums (1024 floats), N%4==0
    int total = npX4 + W + nZero4;
    k_prep<<<(total + 255) / 256, 256, 0, stream>>>(x, lin_l_w, lin_r_w, ro_w1, ro_w2,
                                                    hb, wall, (uint4*)cnt, nX4, npX4, LDD, nZero4);
  }

  // 2) CSR build (rank-based, ushort eidx)
  int nbE = (E + 255) / 256;
  int nbN = (N + 255) / 256;
  k_histrank<<<nbE, 256, 0, stream>>>(dstI, cnt, rankdst, E);
  k_scan1<<<nbN, 256, 0, stream>>>(cnt, off, bsum, N);
  k_scan2<<<1, 256, 0, stream>>>(bsum, boff, nbN);
  k_scan3<<<nbN, 256, 0, stream>>>(off, boff, N);
  k_fill<<<nbE, 256, 0, stream>>>(srcI, rankdst, off, eidx, E);

  const int fusedBlocks = Np / 128;
  const int bnBlocks = (Np * (D / 4) + 255) / 256;

  // 3) layers (hb updated in place by bnrelu)
  for (int l = 0; l < L; ++l) {
    float* lsums = sums + (size_t)l * 2 * D;
    k_fused<true><<<fusedBlocks, 1024, 0, stream>>>(
        hb, wlb + (size_t)l * D * D, wrb + (size_t)l * D * D,
        lin_l_b + (size_t)l * D, off, eidx, pre, lsums, N, E);
    if (l == L - 1)
      k_bnrelu<true><<<bnBlocks, 256, 0, stream>>>(pre, lsums, bn_gamma + (size_t)l * D,
                                                   bn_beta + (size_t)l * D, outH, hb, N, Np, invN);
    else
      k_bnrelu<false><<<bnBlocks, 256, 0, stream>>>(pre, lsums, bn_gamma + (size_t)l * D,
                                                    bn_beta + (size_t)l * D, nullptr, hb, N, Np, invN);
  }

  // 4) readout: z = relu(bn(h @ w1.T + b1)); z overwrites hb
  float* rsums = sums + (size_t)L * 2 * D;
  k_fused<false><<<fusedBlocks, 1024, 0, stream>>>(
      hb, w1b, nullptr, ro_b1, off, eidx, pre, rsums, N, E);
  k_bnrelu<false><<<bnBlocks, 256, 0, stream>>>(pre, rsums, ro_bng, ro_bnb, nullptr, hb, N, Np, invN);
  k_mmfin<<<Np / 128, 256, 0, stream>>>(hb, w2b, ro_b2, amask, outAtom, N);
  k_gather<<<U, 32, 0, stream>>>(outH, uindex, outState, U);
}

// Round 11
// 373.260 us; speedup vs baseline: 1.0378x; 1.0378x over previous
//
#include <hip/hip_runtime.h>

#define D 128

typedef __attribute__((ext_vector_type(8))) short bf16x8;
typedef __attribute__((ext_vector_type(4))) float f32x4;

__device__ __forceinline__ ushort f2b(float f) {
  union { float f; unsigned u; } a; a.f = f;
  unsigned u = a.u;
  return (ushort)((u + 0x7fffu + ((u >> 16) & 1u)) >> 16);  // RNE
}
__device__ __forceinline__ float b2f_lo(unsigned v) {
  union { unsigned u; float f; } a; a.u = v << 16; return a.f;
}
__device__ __forceinline__ float b2f_hi(unsigned v) {
  union { unsigned u; float f; } a; a.u = v & 0xffff0000u; return a.f;
}

// ---------- merged prep: x->bf16 padded, weights->bf16, zero cnt+sums ----------
__global__ void k_prep(const float* __restrict__ x, const float* __restrict__ wl,
                       const float* __restrict__ wr, const float* __restrict__ w1,
                       const float* __restrict__ w2, ushort* __restrict__ hb,
                       ushort* __restrict__ wall, uint4* __restrict__ zr,
                       int nX4, int npX4, int LDD, int nZero4) {
  int i = blockIdx.x * blockDim.x + threadIdx.x;
  if (i < npX4) {
    uint2 pk;
    if (i < nX4) {
      float4 v = *(const float4*)&x[i * 4];
      pk.x = (unsigned)f2b(v.x) | ((unsigned)f2b(v.y) << 16);
      pk.y = (unsigned)f2b(v.z) | ((unsigned)f2b(v.w) << 16);
    } else {
      pk = make_uint2(0u, 0u);
    }
    *(uint2*)&hb[i * 4] = pk;
    return;
  }
  int j = i - npX4;
  int W = 2 * LDD + 2 * D * D;
  if (j < W) {
    float v;
    if (j < LDD) v = wl[j];
    else if (j < 2 * LDD) v = wr[j - LDD];
    else if (j < 2 * LDD + D * D) v = w1[j - 2 * LDD];
    else v = w2[j - 2 * LDD - D * D];
    wall[j] = f2b(v);
    return;
  }
  int z = j - W;
  if (z < nZero4) zr[z] = make_uint4(0u, 0u, 0u, 0u);
}

// ---------- CSR build ----------
__global__ void k_histrank(const int* __restrict__ dstI, int* __restrict__ cnt,
                           int* __restrict__ rankdst, int E) {
  int e = blockIdx.x * blockDim.x + threadIdx.x;
  if (e < E) {
    int d = dstI[e];
    int r = atomicAdd(&cnt[d], 1);
    rankdst[e] = (r << 16) | d;
  }
}
__global__ void k_scan1(const int* __restrict__ cnt, int* __restrict__ off,
                        int* __restrict__ bsum, int n) {
  __shared__ int sd[256];
  int t = threadIdx.x;
  int i = blockIdx.x * 256 + t;
  int x = (i < n) ? cnt[i] : 0;
  sd[t] = x;
  __syncthreads();
  for (int s = 1; s < 256; s <<= 1) {
    int v = (t >= s) ? sd[t - s] : 0;
    __syncthreads();
    sd[t] += v;
    __syncthreads();
  }
  if (i < n) off[i] = sd[t] - x;
  if (t == 255) bsum[blockIdx.x] = sd[255];
}
__global__ void k_scan2(const int* __restrict__ bsum, int* __restrict__ boff, int nb) {
  __shared__ int sd[256];
  int t = threadIdx.x;
  int x = (t < nb) ? bsum[t] : 0;
  sd[t] = x;
  __syncthreads();
  for (int s = 1; s < 256; s <<= 1) {
    int v = (t >= s) ? sd[t - s] : 0;
    __syncthreads();
    sd[t] += v;
    __syncthreads();
  }
  if (t < nb) boff[t] = sd[t] - x;
}
__global__ void k_scan3(int* __restrict__ off, const int* __restrict__ boff, int n) {
  int i = blockIdx.x * blockDim.x + threadIdx.x;
  if (i < n) off[i] += boff[i >> 8];
}
// non-atomic scatter fill, ushort payload
__global__ void k_fill(const int* __restrict__ srcI, const int* __restrict__ rankdst,
                       const int* __restrict__ off, ushort* __restrict__ eidx, int E) {
  int e = blockIdx.x * blockDim.x + threadIdx.x;
  if (e < E) {
    int rd = rankdst[e];
    int d = rd & 0xFFFF;
    eidx[off[d] + (rd >> 16)] = (ushort)srcI[e];
  }
}

#define ACC8(A, V, B)                                             \
  A[B + 0] += b2f_lo(V.x); A[B + 1] += b2f_hi(V.x);               \
  A[B + 2] += b2f_lo(V.y); A[B + 3] += b2f_hi(V.y);               \
  A[B + 4] += b2f_lo(V.z); A[B + 5] += b2f_hi(V.z);               \
  A[B + 6] += b2f_lo(V.w); A[B + 7] += b2f_hi(V.w);

// ---------- XCD-sliced gather-mean: grid = (Np/128) row tiles x 4 feature slices.
// Block b: row tile b>>2, slice s=b&3 (32 feats = one 64B line of each h row).
// Round-robin blockIdx->XCD maps slice s to XCDs {s, s+4}: each XCD's L2 working
// set is one 3.2MB slice of h (+eidx stream) -> L2-resident. 4 thr/row x 16B,
// one fully-coalesced 64B line per edge. Writes aggb slice (dense, coalesced).
__global__ __launch_bounds__(512) void k_aggslice(
    const ushort* __restrict__ hin, const int* __restrict__ off,
    const ushort* __restrict__ eidx, ushort* __restrict__ aggb,
    int N, int E) {
  int b = blockIdx.x;
  int s = b & 3;
  int t = threadIdx.x;
  int lrow = t >> 2;
  int row = (b >> 2) * 128 + lrow;
  int col = s * 32 + ((t & 3) << 3);   // 8-feat (16B) chunk within the slice
  ushort* dst = &aggb[(size_t)row * D + col];
  if (row >= N) { *(uint4*)dst = make_uint4(0u, 0u, 0u, 0u); return; }
  int start = off[row];
  int end = (row == N - 1) ? E : off[row + 1];
  float a[8];
#pragma unroll
  for (int i = 0; i < 8; ++i) a[i] = 0.f;
  const ushort* hbase = hin + col;
#pragma unroll 2
  for (int e = start; e < end; ++e) {
    int sn = eidx[e];
    uint4 v = *(const uint4*)(hbase + (size_t)sn * D);
    ACC8(a, v, 0)
  }
  int deg = end - start;
  float inv = (deg > 0) ? 1.0f / (float)deg : 0.f;
  uint4 o;
  o.x = (unsigned)f2b(a[0] * inv) | ((unsigned)f2b(a[1] * inv) << 16);
  o.y = (unsigned)f2b(a[2] * inv) | ((unsigned)f2b(a[3] * inv) << 16);
  o.z = (unsigned)f2b(a[4] * inv) | ((unsigned)f2b(a[5] * inv) << 16);
  o.w = (unsigned)f2b(a[6] * inv) | ((unsigned)f2b(a[7] * inv) << 16);
  *(uint4*)dst = o;
}

// ---------- MFMA GEMM + bias + col-stats -> pre bf16, sums
// 512 threads, 128x128 tile, 8 waves (4 row x 2 col), mfma_f32_16x16x32_bf16.
// DUAL: out = A1@Wl^T + A2@Wr^T (layer); else out = A1@Wl^T (readout z).
template <bool DUAL>
__global__ __launch_bounds__(512) void k_mm(
    const ushort* __restrict__ A1, const ushort* __restrict__ A2,
    const ushort* __restrict__ Wl, const ushort* __restrict__ Wr,
    const float* __restrict__ bias, ushort* __restrict__ pre,
    float* __restrict__ sums, int N) {
  __shared__ float ls[2 * D];
  int t = threadIdx.x;
  int r0 = blockIdx.x * 128;

  if (t < 2 * D) ls[t] = 0.f;
  __syncthreads();

  int lane = t & 63;
  int wid = t >> 6;
  int wr = wid >> 1, wc = wid & 1;
  int rw = wr * 32, cw = wc * 64;
  int lr = lane & 15, lk = (lane >> 4) * 8;

  f32x4 acc[2][4];
#pragma unroll
  for (int i = 0; i < 2; ++i)
#pragma unroll
    for (int j = 0; j < 4; ++j) acc[i][j] = (f32x4){0.f, 0.f, 0.f, 0.f};

#pragma unroll
  for (int ks = 0; ks < 4; ++ks) {
    int kb = ks * 32 + lk;
    bf16x8 aA[2], aB[2];
#pragma unroll
    for (int rt = 0; rt < 2; ++rt) {
      aA[rt] = *(const bf16x8*)&A1[(size_t)(r0 + rw + rt * 16 + lr) * D + kb];
      if (DUAL) aB[rt] = *(const bf16x8*)&A2[(size_t)(r0 + rw + rt * 16 + lr) * D + kb];
    }
#pragma unroll
    for (int jt = 0; jt < 4; ++jt) {
      bf16x8 b1 = *(const bf16x8*)&Wl[(size_t)(cw + jt * 16 + lr) * D + kb];
      acc[0][jt] = __builtin_amdgcn_mfma_f32_16x16x32_bf16(aA[0], b1, acc[0][jt], 0, 0, 0);
      acc[1][jt] = __builtin_amdgcn_mfma_f32_16x16x32_bf16(aA[1], b1, acc[1][jt], 0, 0, 0);
      if (DUAL) {
        bf16x8 b2 = *(const bf16x8*)&Wr[(size_t)(cw + jt * 16 + lr) * D + kb];
        acc[0][jt] = __builtin_amdgcn_mfma_f32_16x16x32_bf16(aB[0], b2, acc[0][jt], 0, 0, 0);
        acc[1][jt] = __builtin_amdgcn_mfma_f32_16x16x32_bf16(aB[1], b2, acc[1][jt], 0, 0, 0);
      }
    }
  }

  // bias + write pre (bf16) + column stats
  int crow = (lane >> 4) * 4;
#pragma unroll
  for (int jt = 0; jt < 4; ++jt) {
    int col = cw + jt * 16 + lr;
    float bv = bias[col];
    float s1 = 0.f, s2 = 0.f;
#pragma unroll
    for (int rt = 0; rt < 2; ++rt) {
      int rbase = r0 + rw + rt * 16 + crow;
#pragma unroll
      for (int rg = 0; rg < 4; ++rg) {
        int row = rbase + rg;
        if (row < N) {
          float v = acc[rt][jt][rg] + bv;
          pre[(size_t)row * D + col] = f2b(v);
          s1 += v; s2 += v * v;
        }
      }
    }
    s1 += __shfl_xor(s1, 16, 64); s1 += __shfl_xor(s1, 32, 64);
    s2 += __shfl_xor(s2, 16, 64); s2 += __shfl_xor(s2, 32, 64);
    if (lane < 16) {
      atomicAdd(&ls[cw + jt * 16 + lane], s1);
      atomicAdd(&ls[D + cw + jt * 16 + lane], s2);
    }
  }
  __syncthreads();
  if (t < 2 * D) atomicAdd(&sums[t], ls[t]);
}

// ---------- BN + ReLU from bf16 pre; writes bf16 next-activation, opt fp32 ----------
template <bool F32OUT>
__global__ void k_bnrelu(const ushort* __restrict__ pre, const float* __restrict__ sums,
                         const float* __restrict__ gamma, const float* __restrict__ beta,
                         float* __restrict__ fout, ushort* __restrict__ bout,
                         int N, int Np, float invN) {
  int i4 = blockIdx.x * blockDim.x + threadIdx.x;
  if (i4 >= Np * (D / 4)) return;
  int row = i4 >> 5;
  int c4 = (i4 & 31) * 4;
  uint2 pk;
  if (row < N) {
    uint2 pv = *(const uint2*)&pre[(size_t)row * D + c4];
    float4 v = make_float4(b2f_lo(pv.x), b2f_hi(pv.x), b2f_lo(pv.y), b2f_hi(pv.y));
    float4 s = *(const float4*)&sums[c4];
    float4 q = *(const float4*)&sums[D + c4];
    float4 g = *(const float4*)&gamma[c4];
    float4 b = *(const float4*)&beta[c4];
    float mu, var, sc, sh;
    mu = s.x * invN; var = fmaxf(q.x * invN - mu * mu, 0.f);
    sc = g.x * rsqrtf(var + 1e-5f); sh = b.x - mu * sc;
    v.x = fmaxf(fmaf(v.x, sc, sh), 0.f);
    mu = s.y * invN; var = fmaxf(q.y * invN - mu * mu, 0.f);
    sc = g.y * rsqrtf(var + 1e-5f); sh = b.y - mu * sc;
    v.y = fmaxf(fmaf(v.y, sc, sh), 0.f);
    mu = s.z * invN; var = fmaxf(q.z * invN - mu * mu, 0.f);
    sc = g.z * rsqrtf(var + 1e-5f); sh = b.z - mu * sc;
    v.z = fmaxf(fmaf(v.z, sc, sh), 0.f);
    mu = s.w * invN; var = fmaxf(q.w * invN - mu * mu, 0.f);
    sc = g.w * rsqrtf(var + 1e-5f); sh = b.w - mu * sc;
    v.w = fmaxf(fmaf(v.w, sc, sh), 0.f);
    if (F32OUT) *(float4*)&fout[(size_t)row * D + c4] = v;
    pk.x = (unsigned)f2b(v.x) | ((unsigned)f2b(v.y) << 16);
    pk.y = (unsigned)f2b(v.z) | ((unsigned)f2b(v.w) << 16);
  } else {
    pk = make_uint2(0u, 0u);
  }
  *(uint2*)&bout[(size_t)row * D + c4] = pk;
}

// ---------- final GEMM: atom = (z @ W2.T + b2) * mask, fp32 out ----------
__global__ __launch_bounds__(256) void k_mmfin(
    const ushort* __restrict__ A, const ushort* __restrict__ W,
    const float* __restrict__ bias, const float* __restrict__ mask,
    float* __restrict__ out, int N) {
  int t = threadIdx.x;
  int lane = t & 63;
  int wid = t >> 6;
  int wr = wid >> 1, wc = wid & 1;
  int r0 = blockIdx.x * 128 + wr * 64;
  int c0 = wc * 64;
  int lr = lane & 15, lk = (lane >> 4) * 8;

  f32x4 acc[4][4];
#pragma unroll
  for (int i = 0; i < 4; ++i)
#pragma unroll
    for (int j = 0; j < 4; ++j) acc[i][j] = (f32x4){0.f, 0.f, 0.f, 0.f};

#pragma unroll
  for (int ks = 0; ks < 4; ++ks) {
    int kb = ks * 32 + lk;
    bf16x8 a1[4];
#pragma unroll
    for (int rt = 0; rt < 4; ++rt)
      a1[rt] = *(const bf16x8*)&A[(size_t)(r0 + rt * 16 + lr) * D + kb];
#pragma unroll
    for (int jt = 0; jt < 4; ++jt) {
      bf16x8 b1 = *(const bf16x8*)&W[(size_t)(c0 + jt * 16 + lr) * D + kb];
#pragma unroll
      for (int rt = 0; rt < 4; ++rt)
        acc[rt][jt] = __builtin_amdgcn_mfma_f32_16x16x32_bf16(a1[rt], b1, acc[rt][jt], 0, 0, 0);
    }
  }

  int crow = (lane >> 4) * 4;
#pragma unroll
  for (int rt = 0; rt < 4; ++rt) {
    int rbase = r0 + rt * 16 + crow;
#pragma unroll
    for (int jt = 0; jt < 4; ++jt) {
      int col = c0 + jt * 16 + lr;
      float bv = bias[col];
#pragma unroll
      for (int rg = 0; rg < 4; ++rg) {
        int row = rbase + rg;
        if (row < N) {
          float m = mask[row];
          out[(size_t)row * D + col] = (acc[rt][jt][rg] + bv) * m;
        }
      }
    }
  }
}

// ---------- state gather ----------
__global__ void k_gather(const float* __restrict__ h, const int* __restrict__ uidx,
                         float* __restrict__ outp, int U) {
  int u = blockIdx.x;
  int t = threadIdx.x;  // 32 threads
  int s = uidx[u];
  *(float4*)&outp[(size_t)u * D + t * 4] = *(const float4*)&h[(size_t)s * D + t * 4];
}

extern "C" void kernel_launch(void* const* d_in, const int* in_sizes, int n_in,
                              void* d_out, int out_size, void* d_ws, size_t ws_size,
                              hipStream_t stream) {
  const float* x        = (const float*)d_in[0];
  const int*   edge     = (const int*)d_in[1];
  const float* amask    = (const float*)d_in[2];
  const int*   uindex   = (const int*)d_in[3];
  const float* lin_l_w  = (const float*)d_in[4];
  const float* lin_l_b  = (const float*)d_in[5];
  const float* lin_r_w  = (const float*)d_in[6];
  const float* bn_gamma = (const float*)d_in[7];
  const float* bn_beta  = (const float*)d_in[8];
  const float* ro_w1    = (const float*)d_in[9];
  const float* ro_b1    = (const float*)d_in[10];
  const float* ro_bng   = (const float*)d_in[11];
  const float* ro_bnb   = (const float*)d_in[12];
  const float* ro_w2    = (const float*)d_in[13];
  const float* ro_b2    = (const float*)d_in[14];

  const int N = in_sizes[0] / D;
  const int E = in_sizes[1] / 2;
  const int U = in_sizes[3];
  const int L = in_sizes[4] / (D * D);
  const int Np = ((N + 127) / 128) * 128;
  const int LDD = L * D * D;

  const int* srcI = edge;
  const int* dstI = edge + E;

  float* outH     = (float*)d_out;               // [N][D]
  float* outAtom  = outH + (size_t)N * D;        // [N][D]
  float* outState = outAtom + (size_t)N * D;     // [U][D]

  // workspace carve (cnt and sums contiguous for the fused zeroing; 16B aligned)
  char* w = (char*)d_ws;
  ushort* hb   = (ushort*)w; w += (size_t)Np * D * 2;
  ushort* aggb = (ushort*)w; w += (size_t)Np * D * 2;
  ushort* pre  = (ushort*)w; w += (size_t)Np * D * 2;
  ushort* wall = (ushort*)w; w += (size_t)(2 * LDD + 2 * D * D) * 2;
  int*    cnt  = (int*)w;    w += (size_t)N * 4;
  float*  sums = (float*)w;  w += 4 * 2 * D * 4;   // sums0..sums3
  int* off     = (int*)w;    w += (size_t)N * 4;
  int* rankdst = (int*)w;    w += (size_t)E * 4;
  ushort* eidx = (ushort*)w; w += (size_t)((E + 1) & ~1) * 2;
  int* bsum    = (int*)w;    w += 1024;
  int* boff    = (int*)w;    w += 1024;

  ushort* wlb = wall;
  ushort* wrb = wlb + (size_t)LDD;
  ushort* w1b = wrb + (size_t)LDD;
  ushort* w2b = w1b + (size_t)D * D;

  const float invN = 1.0f / (float)N;

  // 1) merged prep: x cast, weight casts, zero cnt+sums
  {
    int nX4 = N * D / 4, npX4 = Np * D / 4;
    int W = 2 * LDD + 2 * D * D;
    int nZero4 = (N + 4 * 2 * D) / 4;           // cnt (N ints) + sums (1024 floats), N%4==0
    int total = npX4 + W + nZero4;
    k_prep<<<(total + 255) / 256, 256, 0, stream>>>(x, lin_l_w, lin_r_w, ro_w1, ro_w2,
                                                    hb, wall, (uint4*)cnt, nX4, npX4, LDD, nZero4);
  }

  // 2) CSR build (rank-based, ushort eidx)
  int nbE = (E + 255) / 256;
  int nbN = (N + 255) / 256;
  k_histrank<<<nbE, 256, 0, stream>>>(dstI, cnt, rankdst, E);
  k_scan1<<<nbN, 256, 0, stream>>>(cnt, off, bsum, N);
  k_scan2<<<1, 256, 0, stream>>>(bsum, boff, nbN);
  k_scan3<<<nbN, 256, 0, stream>>>(off, boff, N);
  k_fill<<<nbE, 256, 0, stream>>>(srcI, rankdst, off, eidx, E);

  const int mmBlocks = Np / 128;
  const int aggBlocks = mmBlocks * 4;            // row tiles x 4 feature slices
  const int bnBlocks = (Np * (D / 4) + 255) / 256;

  // 3) layers: XCD-sliced gather -> dual GEMM + stats -> BN+ReLU
  for (int l = 0; l < L; ++l) {
    float* lsums = sums + (size_t)l * 2 * D;
    k_aggslice<<<aggBlocks, 512, 0, stream>>>(hb, off, eidx, aggb, N, E);
    k_mm<true><<<mmBlocks, 512, 0, stream>>>(
        aggb, hb, wlb + (size_t)l * D * D, wrb + (size_t)l * D * D,
        lin_l_b + (size_t)l * D, pre, lsums, N);
    if (l == L - 1)
      k_bnrelu<true><<<bnBlocks, 256, 0, stream>>>(pre, lsums, bn_gamma + (size_t)l * D,
                                                   bn_beta + (size_t)l * D, outH, hb, N, Np, invN);
    else
      k_bnrelu<false><<<bnBlocks, 256, 0, stream>>>(pre, lsums, bn_gamma + (size_t)l * D,
                                                    bn_beta + (size_t)l * D, nullptr, hb, N, Np, invN);
  }

  // 4) readout: z = relu(bn(h @ w1.T + b1)); z overwrites hb
  float* rsums = sums + (size_t)L * 2 * D;
  k_mm<false><<<mmBlocks, 512, 0, stream>>>(
      hb, nullptr, w1b, nullptr, ro_b1, pre, rsums, N);
  k_bnrelu<false><<<bnBlocks, 256, 0, stream>>>(pre, rsums, ro_bng, ro_bnb, nullptr, hb, N, Np, invN);
  k_mmfin<<<mmBlocks, 256, 0, stream>>>(hb, w2b, ro_b2, amask, outAtom, N);
  k_gather<<<U, 32, 0, stream>>>(outH, uindex, outState, U);
}

// Round 14
// 309.837 us; speedup vs baseline: 1.2503x; 1.2047x over previous
//
#include <hip/hip_runtime.h>

#define D 128
#define LDA 136   // LDS agg row stride in ushorts: 272B, 16B-aligned

typedef __attribute__((ext_vector_type(8))) short bf16x8;
typedef __attribute__((ext_vector_type(4))) float f32x4;

__device__ __forceinline__ ushort f2b(float f) {
  union { float f; unsigned u; } a; a.f = f;
  unsigned u = a.u;
  return (ushort)((u + 0x7fffu + ((u >> 16) & 1u)) >> 16);  // RNE
}
__device__ __forceinline__ float b2f_lo(unsigned v) {
  union { unsigned u; float f; } a; a.u = v << 16; return a.f;
}
__device__ __forceinline__ float b2f_hi(unsigned v) {
  union { unsigned u; float f; } a; a.u = v & 0xffff0000u; return a.f;
}

// ---------- merged prep: x->bf16 padded, weights->bf16, zero cnt+sums ----------
__global__ void k_prep(const float* __restrict__ x, const float* __restrict__ wl,
                       const float* __restrict__ wr, const float* __restrict__ w1,
                       const float* __restrict__ w2, ushort* __restrict__ hb,
                       ushort* __restrict__ wall, uint4* __restrict__ zr,
                       int nX4, int npX4, int LDD, int nZero4) {
  int i = blockIdx.x * blockDim.x + threadIdx.x;
  if (i < npX4) {
    uint2 pk;
    if (i < nX4) {
      float4 v = *(const float4*)&x[i * 4];
      pk.x = (unsigned)f2b(v.x) | ((unsigned)f2b(v.y) << 16);
      pk.y = (unsigned)f2b(v.z) | ((unsigned)f2b(v.w) << 16);
    } else {
      pk = make_uint2(0u, 0u);
    }
    *(uint2*)&hb[i * 4] = pk;
    return;
  }
  int j = i - npX4;
  int W = 2 * LDD + 2 * D * D;
  if (j < W) {
    float v;
    if (j < LDD) v = wl[j];
    else if (j < 2 * LDD) v = wr[j - LDD];
    else if (j < 2 * LDD + D * D) v = w1[j - 2 * LDD];
    else v = w2[j - 2 * LDD - D * D];
    wall[j] = f2b(v);
    return;
  }
  int z = j - W;
  if (z < nZero4) zr[z] = make_uint4(0u, 0u, 0u, 0u);
}

// ---------- CSR build ----------
__global__ void k_histrank(const int* __restrict__ dstI, int* __restrict__ cnt,
                           int* __restrict__ rankdst, int E) {
  int e = blockIdx.x * blockDim.x + threadIdx.x;
  if (e < E) {
    int d = dstI[e];
    int r = atomicAdd(&cnt[d], 1);
    rankdst[e] = (r << 16) | d;
  }
}
__global__ void k_scan1(const int* __restrict__ cnt, int* __restrict__ off,
                        int* __restrict__ bsum, int n) {
  __shared__ int sd[256];
  int t = threadIdx.x;
  int i = blockIdx.x * 256 + t;
  int x = (i < n) ? cnt[i] : 0;
  sd[t] = x;
  __syncthreads();
  for (int s = 1; s < 256; s <<= 1) {
    int v = (t >= s) ? sd[t - s] : 0;
    __syncthreads();
    sd[t] += v;
    __syncthreads();
  }
  if (i < n) off[i] = sd[t] - x;
  if (t == 255) bsum[blockIdx.x] = sd[255];
}
__global__ void k_scan2(const int* __restrict__ bsum, int* __restrict__ boff, int nb) {
  __shared__ int sd[256];
  int t = threadIdx.x;
  int x = (t < nb) ? bsum[t] : 0;
  sd[t] = x;
  __syncthreads();
  for (int s = 1; s < 256; s <<= 1) {
    int v = (t >= s) ? sd[t - s] : 0;
    __syncthreads();
    sd[t] += v;
    __syncthreads();
  }
  if (t < nb) boff[t] = sd[t] - x;
}
__global__ void k_scan3(int* __restrict__ off, const int* __restrict__ boff, int n) {
  int i = blockIdx.x * blockDim.x + threadIdx.x;
  if (i < n) off[i] += boff[i >> 8];
}
// non-atomic scatter fill, ushort payload
__global__ void k_fill(const int* __restrict__ srcI, const int* __restrict__ rankdst,
                       const int* __restrict__ off, ushort* __restrict__ eidx, int E) {
  int e = blockIdx.x * blockDim.x + threadIdx.x;
  if (e < E) {
    int rd = rankdst[e];
    int d = rd & 0xFFFF;
    eidx[off[d] + (rd >> 16)] = (ushort)srcI[e];
  }
}

#define ACC8(A, V, B)                                             \
  A[B + 0] += b2f_lo(V.x); A[B + 1] += b2f_hi(V.x);               \
  A[B + 2] += b2f_lo(V.y); A[B + 3] += b2f_hi(V.y);               \
  A[B + 4] += b2f_lo(V.z); A[B + 5] += b2f_hi(V.z);               \
  A[B + 6] += b2f_lo(V.w); A[B + 7] += b2f_hi(V.w);

// ---------- fused: [gather-mean -> LDS] + dual GEMM + bias + col-stats -> pre bf16, sums
// 1024 threads (16 waves), 128-row x 128-col tile.  (r7-proven structure, VGPR 32)
// Gather: 8 threads/row, 16 feats (32B) each, single chain, ushort edge indices.
// GEMM: 4x4 wave grid, 32x32 per wave, acc[2][2], mfma_f32_16x16x32_bf16.
template <bool AGG>
__global__ __launch_bounds__(1024, 8) void k_fused(
    const ushort* __restrict__ hin, const ushort* __restrict__ Wl,
    const ushort* __restrict__ Wr, const float* __restrict__ bias,
    const int* __restrict__ off, const ushort* __restrict__ eidx,
    ushort* __restrict__ pre, float* __restrict__ sums, int N, int E) {
  __shared__ ushort aggS[128 * LDA];
  __shared__ float ls[2 * D];
  int t = threadIdx.x;
  int r0 = blockIdx.x * 128;

  if (t < 2 * D) ls[t] = 0.f;

  if (AGG) {
    // gather-mean into LDS: 8 threads per row, 16 features (32B) each
    int lrow = t >> 3;
    int row = r0 + lrow;
    int part = (t & 7) << 4;
    float a[16];
#pragma unroll
    for (int i = 0; i < 16; ++i) a[i] = 0.f;
    int start = 0, end = 0;
    if (row < N) { start = off[row]; end = (row == N - 1) ? E : off[row + 1]; }
    const ushort* hbase = hin + part;
#pragma unroll 2
    for (int e = start; e < end; ++e) {
      int sn = eidx[e];
      const uint4* p = (const uint4*)(hbase + (size_t)sn * D);
      uint4 v0 = p[0], v1 = p[1];
      ACC8(a, v0, 0) ACC8(a, v1, 8)
    }
    int deg = end - start;
    float inv = (deg > 0) ? 1.0f / (float)deg : 0.f;
    unsigned o[8];
#pragma unroll
    for (int i = 0; i < 8; ++i)
      o[i] = (unsigned)f2b(a[2 * i] * inv) | ((unsigned)f2b(a[2 * i + 1] * inv) << 16);
    uint4* dst = (uint4*)&aggS[lrow * LDA + part];
    dst[0] = make_uint4(o[0], o[1], o[2], o[3]);
    dst[1] = make_uint4(o[4], o[5], o[6], o[7]);
  }
  __syncthreads();

  // MFMA phase: 16 waves, 4 row-groups x 4 col-groups, 32x32 per wave
  int lane = t & 63;
  int wid = t >> 6;
  int wr = wid >> 2, wc = wid & 3;
  int rw = wr * 32, cw = wc * 32;
  int lr = lane & 15, lk = (lane >> 4) * 8;

  f32x4 acc[2][2];
#pragma unroll
  for (int i = 0; i < 2; ++i)
#pragma unroll
    for (int j = 0; j < 2; ++j) acc[i][j] = (f32x4){0.f, 0.f, 0.f, 0.f};

#pragma unroll
  for (int ks = 0; ks < 4; ++ks) {
    int kb = ks * 32 + lk;
    bf16x8 aA[2], aB[2];
#pragma unroll
    for (int rt = 0; rt < 2; ++rt) {
      if (AGG) {
        aA[rt] = *(const bf16x8*)&aggS[(rw + rt * 16 + lr) * LDA + kb];
        aB[rt] = *(const bf16x8*)&hin[(size_t)(r0 + rw + rt * 16 + lr) * D + kb];
      } else {
        aA[rt] = *(const bf16x8*)&hin[(size_t)(r0 + rw + rt * 16 + lr) * D + kb];
      }
    }
#pragma unroll
    for (int jt = 0; jt < 2; ++jt) {
      bf16x8 b1 = *(const bf16x8*)&Wl[(size_t)(cw + jt * 16 + lr) * D + kb];
      acc[0][jt] = __builtin_amdgcn_mfma_f32_16x16x32_bf16(aA[0], b1, acc[0][jt], 0, 0, 0);
      acc[1][jt] = __builtin_amdgcn_mfma_f32_16x16x32_bf16(aA[1], b1, acc[1][jt], 0, 0, 0);
      if (AGG) {
        bf16x8 b2 = *(const bf16x8*)&Wr[(size_t)(cw + jt * 16 + lr) * D + kb];
        acc[0][jt] = __builtin_amdgcn_mfma_f32_16x16x32_bf16(aB[0], b2, acc[0][jt], 0, 0, 0);
        acc[1][jt] = __builtin_amdgcn_mfma_f32_16x16x32_bf16(aB[1], b2, acc[1][jt], 0, 0, 0);
      }
    }
  }

  // bias + write pre (bf16) + column stats
  int crow = (lane >> 4) * 4;
#pragma unroll
  for (int jt = 0; jt < 2; ++jt) {
    int col = cw + jt * 16 + lr;
    float bv = bias[col];
    float s1 = 0.f, s2 = 0.f;
#pragma unroll
    for (int rt = 0; rt < 2; ++rt) {
      int rbase = r0 + rw + rt * 16 + crow;
#pragma unroll
      for (int rg = 0; rg < 4; ++rg) {
        int row = rbase + rg;
        if (row < N) {
          float v = acc[rt][jt][rg] + bv;
          pre[(size_t)row * D + col] = f2b(v);
          s1 += v; s2 += v * v;
        }
      }
    }
    s1 += __shfl_xor(s1, 16, 64); s1 += __shfl_xor(s1, 32, 64);
    s2 += __shfl_xor(s2, 16, 64); s2 += __shfl_xor(s2, 32, 64);
    if (lane < 16) {
      atomicAdd(&ls[cw + jt * 16 + lane], s1);
      atomicAdd(&ls[D + cw + jt * 16 + lane], s2);
    }
  }
  __syncthreads();
  if (t < 2 * D) atomicAdd(&sums[t], ls[t]);
}

// ---------- BN + ReLU from bf16 pre; writes bf16 next-activation, opt fp32 ----------
template <bool F32OUT>
__global__ void k_bnrelu(const ushort* __restrict__ pre, const float* __restrict__ sums,
                         const float* __restrict__ gamma, const float* __restrict__ beta,
                         float* __restrict__ fout, ushort* __restrict__ bout,
                         int N, int Np, float invN) {
  int i4 = blockIdx.x * blockDim.x + threadIdx.x;
  if (i4 >= Np * (D / 4)) return;
  int row = i4 >> 5;
  int c4 = (i4 & 31) * 4;
  uint2 pk;
  if (row < N) {
    uint2 pv = *(const uint2*)&pre[(size_t)row * D + c4];
    float4 v = make_float4(b2f_lo(pv.x), b2f_hi(pv.x), b2f_lo(pv.y), b2f_hi(pv.y));
    float4 s = *(const float4*)&sums[c4];
    float4 q = *(const float4*)&sums[D + c4];
    float4 g = *(const float4*)&gamma[c4];
    float4 b = *(const float4*)&beta[c4];
    float mu, var, sc, sh;
    mu = s.x * invN; var = fmaxf(q.x * invN - mu * mu, 0.f);
    sc = g.x * rsqrtf(var + 1e-5f); sh = b.x - mu * sc;
    v.x = fmaxf(fmaf(v.x, sc, sh), 0.f);
    mu = s.y * invN; var = fmaxf(q.y * invN - mu * mu, 0.f);
    sc = g.y * rsqrtf(var + 1e-5f); sh = b.y - mu * sc;
    v.y = fmaxf(fmaf(v.y, sc, sh), 0.f);
    mu = s.z * invN; var = fmaxf(q.z * invN - mu * mu, 0.f);
    sc = g.z * rsqrtf(var + 1e-5f); sh = b.z - mu * sc;
    v.z = fmaxf(fmaf(v.z, sc, sh), 0.f);
    mu = s.w * invN; var = fmaxf(q.w * invN - mu * mu, 0.f);
    sc = g.w * rsqrtf(var + 1e-5f); sh = b.w - mu * sc;
    v.w = fmaxf(fmaf(v.w, sc, sh), 0.f);
    if (F32OUT) *(float4*)&fout[(size_t)row * D + c4] = v;
    pk.x = (unsigned)f2b(v.x) | ((unsigned)f2b(v.y) << 16);
    pk.y = (unsigned)f2b(v.z) | ((unsigned)f2b(v.w) << 16);
  } else {
    pk = make_uint2(0u, 0u);
  }
  *(uint2*)&bout[(size_t)row * D + c4] = pk;
}

// bf16 fragment load with on-the-fly BN+ReLU (per-k scale/shift from LDS)
__device__ __forceinline__ bf16x8 loadBfragBN(const ushort* __restrict__ p,
                                              const float* __restrict__ scshS, int kb) {
  bf16x8 f = *(const bf16x8*)p;
#pragma unroll
  for (int q = 0; q < 8; ++q) {
    float x = b2f_lo((unsigned)(ushort)f[q]);
    x = fmaxf(fmaf(x, scshS[kb + q], scshS[D + kb + q]), 0.f);
    f[q] = (short)f2b(x);
  }
  return f;
}

// ---------- final GEMM with deferred BN on A: atom = (relu(bn(z_pre)) @ W2.T + b2)*mask ----------
__global__ __launch_bounds__(256) void k_mmfin(
    const ushort* __restrict__ A, const float* __restrict__ psums,
    const float* __restrict__ pgamma, const float* __restrict__ pbeta,
    const ushort* __restrict__ W, const float* __restrict__ bias,
    const float* __restrict__ mask, float* __restrict__ out, int N, float invN) {
  __shared__ float scshS[2 * D];
  int t = threadIdx.x;
  if (t < D) {
    float mu = psums[t] * invN;
    float var = fmaxf(psums[D + t] * invN - mu * mu, 0.f);
    float s = pgamma[t] * rsqrtf(var + 1e-5f);
    scshS[t] = s;
    scshS[D + t] = pbeta[t] - mu * s;
  }
  __syncthreads();

  int lane = t & 63;
  int wid = t >> 6;
  int wr = wid >> 1, wc = wid & 1;
  int r0 = blockIdx.x * 128 + wr * 64;
  int c0 = wc * 64;
  int lr = lane & 15, lk = (lane >> 4) * 8;

  f32x4 acc[4][4];
#pragma unroll
  for (int i = 0; i < 4; ++i)
#pragma unroll
    for (int j = 0; j < 4; ++j) acc[i][j] = (f32x4){0.f, 0.f, 0.f, 0.f};

#pragma unroll
  for (int ks = 0; ks < 4; ++ks) {
    int kb = ks * 32 + lk;
    bf16x8 a1[4];
#pragma unroll
    for (int rt = 0; rt < 4; ++rt)
      a1[rt] = loadBfragBN(&A[(size_t)(r0 + rt * 16 + lr) * D + kb], scshS, kb);
#pragma unroll
    for (int jt = 0; jt < 4; ++jt) {
      bf16x8 b1 = *(const bf16x8*)&W[(size_t)(c0 + jt * 16 + lr) * D + kb];
#pragma unroll
      for (int rt = 0; rt < 4; ++rt)
        acc[rt][jt] = __builtin_amdgcn_mfma_f32_16x16x32_bf16(a1[rt], b1, acc[rt][jt], 0, 0, 0);
    }
  }

  int crow = (lane >> 4) * 4;
#pragma unroll
  for (int rt = 0; rt < 4; ++rt) {
    int rbase = r0 + rt * 16 + crow;
#pragma unroll
    for (int jt = 0; jt < 4; ++jt) {
      int col = c0 + jt * 16 + lr;
      float bv = bias[col];
#pragma unroll
      for (int rg = 0; rg < 4; ++rg) {
        int row = rbase + rg;
        if (row < N) {
          float m = mask[row];
          out[(size_t)row * D + col] = (acc[rt][jt][rg] + bv) * m;
        }
      }
    }
  }
}

// ---------- state gather ----------
__global__ void k_gather(const float* __restrict__ h, const int* __restrict__ uidx,
                         float* __restrict__ outp, int U) {
  int u = blockIdx.x;
  int t = threadIdx.x;  // 32 threads
  int s = uidx[u];
  *(float4*)&outp[(size_t)u * D + t * 4] = *(const float4*)&h[(size_t)s * D + t * 4];
}

extern "C" void kernel_launch(void* const* d_in, const int* in_sizes, int n_in,
                              void* d_out, int out_size, void* d_ws, size_t ws_size,
                              hipStream_t stream) {
  const float* x        = (const float*)d_in[0];
  const int*   edge     = (const int*)d_in[1];
  const float* amask    = (const float*)d_in[2];
  const int*   uindex   = (const int*)d_in[3];
  const float* lin_l_w  = (const float*)d_in[4];
  const float* lin_l_b  = (const float*)d_in[5];
  const float* lin_r_w  = (const float*)d_in[6];
  const float* bn_gamma = (const float*)d_in[7];
  const float* bn_beta  = (const float*)d_in[8];
  const float* ro_w1    = (const float*)d_in[9];
  const float* ro_b1    = (const float*)d_in[10];
  const float* ro_bng   = (const float*)d_in[11];
  const float* ro_bnb   = (const float*)d_in[12];
  const float* ro_w2    = (const float*)d_in[13];
  const float* ro_b2    = (const float*)d_in[14];

  const int N = in_sizes[0] / D;
  const int E = in_sizes[1] / 2;
  const int U = in_sizes[3];
  const int L = in_sizes[4] / (D * D);
  const int Np = ((N + 127) / 128) * 128;
  const int LDD = L * D * D;

  const int* srcI = edge;
  const int* dstI = edge + E;

  float* outH     = (float*)d_out;               // [N][D]
  float* outAtom  = outH + (size_t)N * D;        // [N][D]
  float* outState = outAtom + (size_t)N * D;     // [U][D]

  // workspace carve (cnt and sums contiguous for the fused zeroing; 16B aligned)
  char* w = (char*)d_ws;
  ushort* hb   = (ushort*)w; w += (size_t)Np * D * 2;
  ushort* pre  = (ushort*)w; w += (size_t)Np * D * 2;
  ushort* wall = (ushort*)w; w += (size_t)(2 * LDD + 2 * D * D) * 2;
  int*    cnt  = (int*)w;    w += (size_t)N * 4;
  float*  sums = (float*)w;  w += 4 * 2 * D * 4;   // sums0..sums3
  int* off     = (int*)w;    w += (size_t)N * 4;
  int* rankdst = (int*)w;    w += (size_t)E * 4;
  ushort* eidx = (ushort*)w; w += (size_t)((E + 1) & ~1) * 2;
  int* bsum    = (int*)w;    w += 1024;
  int* boff    = (int*)w;    w += 1024;

  ushort* wlb = wall;
  ushort* wrb = wlb + (size_t)LDD;
  ushort* w1b = wrb + (size_t)LDD;
  ushort* w2b = w1b + (size_t)D * D;

  const float invN = 1.0f / (float)N;

  // 1) merged prep: x cast (bf16), weight casts, zero cnt+sums
  {
    int nX4 = N * D / 4, npX4 = Np * D / 4;
    int W = 2 * LDD + 2 * D * D;
    int nZero4 = (N + 4 * 2 * D) / 4;           // cnt (N ints) + sums (1024 floats), N%4==0
    int total = npX4 + W + nZero4;
    k_prep<<<(total + 255) / 256, 256, 0, stream>>>(x, lin_l_w, lin_r_w, ro_w1, ro_w2,
                                                    hb, wall, (uint4*)cnt, nX4, npX4, LDD, nZero4);
  }

  // 2) CSR build (rank-based, ushort eidx)
  int nbE = (E + 255) / 256;
  int nbN = (N + 255) / 256;
  k_histrank<<<nbE, 256, 0, stream>>>(dstI, cnt, rankdst, E);
  k_scan1<<<nbN, 256, 0, stream>>>(cnt, off, bsum, N);
  k_scan2<<<1, 256, 0, stream>>>(bsum, boff, nbN);
  k_scan3<<<nbN, 256, 0, stream>>>(off, boff, N);
  k_fill<<<nbE, 256, 0, stream>>>(srcI, rankdst, off, eidx, E);

  const int fusedBlocks = Np / 128;
  const int bnBlocks = (Np * (D / 4) + 255) / 256;

  // 3) layers (hb updated in place by bnrelu)
  for (int l = 0; l < L; ++l) {
    float* lsums = sums + (size_t)l * 2 * D;
    k_fused<true><<<fusedBlocks, 1024, 0, stream>>>(
        hb, wlb + (size_t)l * D * D, wrb + (size_t)l * D * D,
        lin_l_b + (size_t)l * D, off, eidx, pre, lsums, N, E);
    if (l == L - 1)
      k_bnrelu<true><<<bnBlocks, 256, 0, stream>>>(pre, lsums, bn_gamma + (size_t)l * D,
                                                   bn_beta + (size_t)l * D, outH, hb, N, Np, invN);
    else
      k_bnrelu<false><<<bnBlocks, 256, 0, stream>>>(pre, lsums, bn_gamma + (size_t)l * D,
                                                    bn_beta + (size_t)l * D, nullptr, hb, N, Np, invN);
  }

  // 4) readout: z-pre GEMM + stats, then final GEMM with deferred BN on A
  float* rsums = sums + (size_t)L * 2 * D;
  k_fused<false><<<fusedBlocks, 1024, 0, stream>>>(
      hb, w1b, nullptr, ro_b1, off, eidx, pre, rsums, N, E);
  k_mmfin<<<fusedBlocks, 256, 0, stream>>>(pre, rsums, ro_bng, ro_bnb,
                                           w2b, ro_b2, amask, outAtom, N, invN);
  k_gather<<<U, 32, 0, stream>>>(outH, uindex, outState, U);
}